// Round 1
// baseline (592.089 us; speedup 1.0000x reference)
//
#include <hip/hip_runtime.h>

// SparseConvTransposeBlock: gather -> per-offset 64x64 GEMM (bf16 MFMA, fp32 acc)
// -> scatter atomic-fadd -> BatchNorm(train) -> ReLU.
//
// Numerics: inputs rounded to bf16 for MFMA; fp32 accumulation. Expected error
// ~1e-2 vs fp32 ref; harness threshold is 2% of ref max (~0.1275).
//
// NOTE: the conv bias cancels exactly in training-mode BN that immediately
// follows it: y = (acc + b - (mean_acc + b)) * rsqrt(var) * gamma + beta
//             = (acc - mean_acc) * rsqrt(var) * gamma + beta.
// var is also shift-invariant. So bias is not needed in the compute.

#define C_DIM 64
#define LDS_STRIDE 72  // bf16 elems per Wt row: 64 + 8 pad; 144 B, 16B-aligned

typedef __bf16 bf16_t;
typedef bf16_t bf16x8 __attribute__((ext_vector_type(8)));
typedef float floatx4 __attribute__((ext_vector_type(4)));

__global__ __launch_bounds__(256)
void k1_scatter_gemm(const float* __restrict__ features,
                     const float* __restrict__ weight,
                     const int* __restrict__ pairs_in,
                     const int* __restrict__ pairs_out,
                     float* __restrict__ out,
                     int P, int rows_per_block)
{
    __shared__ bf16_t Wt[C_DIM * LDS_STRIDE];

    const int k   = blockIdx.y;
    const int tid = threadIdx.x;

    // Stage W_k^T into LDS as bf16: Wt[d][c] = W[k][c][d].
    const float* Wk = weight + (size_t)k * C_DIM * C_DIM;
    for (int i = tid; i < C_DIM * C_DIM; i += 256) {
        int c = i >> 6, d = i & 63;
        Wt[d * LDS_STRIDE + c] = (bf16_t)Wk[i];
    }
    __syncthreads();

    const int wave = tid >> 6;
    const int lane = tid & 63;
    const int quad = lane >> 4;   // lane>>4 in 0..3
    const int col  = lane & 15;

    // B fragments (W_k), register-resident for the whole block:
    // lane L holds B[kk = quad*8 + j + 32*ks][n = col + 16*nt] = Wt[n][kk].
    bf16x8 bfrag[2][4];
    #pragma unroll
    for (int ks = 0; ks < 2; ++ks)
        #pragma unroll
        for (int nt = 0; nt < 4; ++nt)
            bfrag[ks][nt] =
                *(const bf16x8*)&Wt[(col + 16 * nt) * LDS_STRIDE + quad * 8 + 32 * ks];

    const int* __restrict__ pin  = pairs_in  + (size_t)k * P;
    const int* __restrict__ pout = pairs_out + (size_t)k * P;

    const int p0   = blockIdx.x * rows_per_block;
    const int pend = min(p0 + rows_per_block, P);

    for (int base = p0 + wave * 16; base < pend; base += 64) {
        // This lane mirrors row (base + col); quads replicate the 16 rows.
        int prow    = base + col;
        int clamped = (prow < pend) ? prow : (pend - 1);
        int in_idx  = pin[clamped];
        int out_idx = pout[clamped];

        // Gather A fragments straight from global in MFMA A-layout:
        // A[m = col][kk = quad*8 + j + 32*ks] = features[in_idx][kk].
        const float* src = features + (size_t)in_idx * C_DIM + quad * 8;
        float4 f0 = *(const float4*)(src);
        float4 f1 = *(const float4*)(src + 4);
        float4 f2 = *(const float4*)(src + 32);
        float4 f3 = *(const float4*)(src + 36);

        bf16x8 a0, a1;
        a0[0] = (bf16_t)f0.x; a0[1] = (bf16_t)f0.y; a0[2] = (bf16_t)f0.z; a0[3] = (bf16_t)f0.w;
        a0[4] = (bf16_t)f1.x; a0[5] = (bf16_t)f1.y; a0[6] = (bf16_t)f1.z; a0[7] = (bf16_t)f1.w;
        a1[0] = (bf16_t)f2.x; a1[1] = (bf16_t)f2.y; a1[2] = (bf16_t)f2.z; a1[3] = (bf16_t)f2.w;
        a1[4] = (bf16_t)f3.x; a1[5] = (bf16_t)f3.y; a1[6] = (bf16_t)f3.z; a1[7] = (bf16_t)f3.w;

        floatx4 acc0 = {0.f, 0.f, 0.f, 0.f};
        floatx4 acc1 = {0.f, 0.f, 0.f, 0.f};
        floatx4 acc2 = {0.f, 0.f, 0.f, 0.f};
        floatx4 acc3 = {0.f, 0.f, 0.f, 0.f};

        acc0 = __builtin_amdgcn_mfma_f32_16x16x32_bf16(a0, bfrag[0][0], acc0, 0, 0, 0);
        acc0 = __builtin_amdgcn_mfma_f32_16x16x32_bf16(a1, bfrag[1][0], acc0, 0, 0, 0);
        acc1 = __builtin_amdgcn_mfma_f32_16x16x32_bf16(a0, bfrag[0][1], acc1, 0, 0, 0);
        acc1 = __builtin_amdgcn_mfma_f32_16x16x32_bf16(a1, bfrag[1][1], acc1, 0, 0, 0);
        acc2 = __builtin_amdgcn_mfma_f32_16x16x32_bf16(a0, bfrag[0][2], acc2, 0, 0, 0);
        acc2 = __builtin_amdgcn_mfma_f32_16x16x32_bf16(a1, bfrag[1][2], acc2, 0, 0, 0);
        acc3 = __builtin_amdgcn_mfma_f32_16x16x32_bf16(a0, bfrag[0][3], acc3, 0, 0, 0);
        acc3 = __builtin_amdgcn_mfma_f32_16x16x32_bf16(a1, bfrag[1][3], acc3, 0, 0, 0);

        // Scatter: C/D layout is row m = quad*4 + r, col n = col + 16*nt.
        #pragma unroll
        for (int r = 0; r < 4; ++r) {
            int m = quad * 4 + r;
            int g = __shfl(out_idx, m);      // lane m (<16) holds row base+m's index
            if (base + m < pend) {
                float* dst = out + (size_t)g * C_DIM + col;
                unsafeAtomicAdd(dst +  0, acc0[r]);
                unsafeAtomicAdd(dst + 16, acc1[r]);
                unsafeAtomicAdd(dst + 32, acc2[r]);
                unsafeAtomicAdd(dst + 48, acc3[r]);
            }
        }
    }
}

// Per-channel sum and sum-of-squares over all rows of acc (the pre-BN output).
__global__ __launch_bounds__(256)
void k2_stats(const float* __restrict__ acc, float* __restrict__ sums, int n_rows)
{
    int tid = threadIdx.x;
    int ch  = tid & 63;
    int sub = tid >> 6;  // 0..3

    float s = 0.f, s2 = 0.f;
    for (int r = blockIdx.x * 4 + sub; r < n_rows; r += gridDim.x * 4) {
        float v = acc[(size_t)r * C_DIM + ch];
        s  += v;
        s2 += v * v;
    }

    __shared__ float red[256];
    red[tid] = s;
    __syncthreads();
    if (tid < 64) {
        float t = red[tid] + red[tid + 64] + red[tid + 128] + red[tid + 192];
        atomicAdd(&sums[ch], t);
    }
    __syncthreads();
    red[tid] = s2;
    __syncthreads();
    if (tid < 64) {
        float t = red[tid] + red[tid + 64] + red[tid + 128] + red[tid + 192];
        atomicAdd(&sums[64 + ch], t);
    }
}

// In-place BN (training stats) + ReLU. Bias cancels (see header comment).
__global__ __launch_bounds__(256)
void k3_bn_relu(float* __restrict__ out, const float* __restrict__ sums,
                const float* __restrict__ gamma, const float* __restrict__ beta,
                int n_rows)
{
    int tid = blockIdx.x * 256 + threadIdx.x;
    int ch0 = (tid * 4) & 63;  // stride is a multiple of 64 elems -> fixed channels
    float inv_n = 1.0f / (float)n_rows;

    float sc[4], sh[4];
    #pragma unroll
    for (int j = 0; j < 4; ++j) {
        int ch    = ch0 + j;
        float m   = sums[ch] * inv_n;
        float var = sums[64 + ch] * inv_n - m * m;
        float inv = rsqrtf(var + 1e-5f);
        float g   = gamma[ch] * inv;
        sc[j] = g;
        sh[j] = beta[ch] - m * g;
    }

    size_t total = (size_t)n_rows * C_DIM / 4;
    for (size_t i = tid; i < total; i += (size_t)gridDim.x * 256) {
        float4 v = ((const float4*)out)[i];
        v.x = fmaxf(v.x * sc[0] + sh[0], 0.f);
        v.y = fmaxf(v.y * sc[1] + sh[1], 0.f);
        v.z = fmaxf(v.z * sc[2] + sh[2], 0.f);
        v.w = fmaxf(v.w * sc[3] + sh[3], 0.f);
        ((float4*)out)[i] = v;
    }
}

extern "C" void kernel_launch(void* const* d_in, const int* in_sizes, int n_in,
                              void* d_out, int out_size, void* d_ws, size_t ws_size,
                              hipStream_t stream)
{
    const float* features  = (const float*)d_in[0];
    const float* weight    = (const float*)d_in[1];
    // d_in[2] = bias  (cancels in training-mode BN; unused by construction)
    const float* gamma     = (const float*)d_in[3];
    const float* beta      = (const float*)d_in[4];
    const int*   pairs_in  = (const int*)d_in[5];
    const int*   pairs_out = (const int*)d_in[6];
    // d_in[7] = n_out on device; derive host-side instead:

    const int n_out = out_size / C_DIM;
    const int K3    = in_sizes[1] / (C_DIM * C_DIM);
    const int P     = in_sizes[5] / K3;

    float* out  = (float*)d_out;
    float* sums = (float*)d_ws;  // [64] sum, [64] sumsq

    hipMemsetAsync(d_out, 0, (size_t)out_size * sizeof(float), stream);
    hipMemsetAsync(d_ws, 0, 128 * sizeof(float), stream);

    const int rows_per_block = 512;
    dim3 g1((P + rows_per_block - 1) / rows_per_block, K3);
    k1_scatter_gemm<<<g1, 256, 0, stream>>>(features, weight, pairs_in, pairs_out,
                                            out, P, rows_per_block);

    k2_stats<<<dim3(512), 256, 0, stream>>>(out, sums, n_out);

    k3_bn_relu<<<dim3(512), 256, 0, stream>>>(out, sums, gamma, beta, n_out);
}